// Round 10
// baseline (1418.021 us; speedup 1.0000x reference)
//
#include <hip/hip_runtime.h>

typedef unsigned short u16;
typedef unsigned int u32;

__device__ __forceinline__ float bf2f(u16 u){ union{u32 i; float f;} v; v.i=((u32)u)<<16; return v.f; }
__device__ __forceinline__ float bflo(u32 p){ union{u32 i; float f;} v; v.i=p<<16; return v.f; }
__device__ __forceinline__ float bfhi(u32 p){ union{u32 i; float f;} v; v.i=p&0xffff0000u; return v.f; }
__device__ __forceinline__ u16 f2bf(float x){ union{float f; u32 i;} v; v.f=x; u32 b=v.i;
  return (u16)((b + 0x7fffu + ((b>>16)&1u))>>16); }

#define HEADS 4
#define HHID 256   // HEADS*HID
#define NT 16      // nodes per block in k_xlr

// ---- fill d_out with a float value (diagnostic only) ----
__global__ void TopoAggregator_33217277067466_kernel(float* __restrict__ out, int n, float val){
  for(int i = blockIdx.x*blockDim.x + threadIdx.x; i < n; i += gridDim.x*blockDim.x)
    out[i] = val;
}

// ---- post-hoc invariant marker: touches d_out ONLY on failure ----
// codes: 400 CSR broken, 500 h all-zero
__global__ void k_marker(const int* __restrict__ rowstart, const float* __restrict__ h,
                         float* __restrict__ out, int N, int Et){
  if(threadIdx.x!=0 || blockIdx.x!=0) return;
  float M = 0.f;
  if(rowstart[N] != Et) M = 400.f;
  else {
    int allz = 1;
    for(int i=0;i<128;i++) if(h[i]!=0.f){ allz=0; break; }
    if(allz) M = 500.f;
  }
  if(M != 0.f) out[0] = M;
}

// ---- zero counts[N] and relmean[16] ----
__global__ void k_zero(int* __restrict__ counts, float* __restrict__ relmean, int N){
  int i = blockIdx.x*blockDim.x + threadIdx.x;
  if(i < N) counts[i] = 0;
  if(i < 16) relmean[i] = 0.f;
}

// ---- relation mean over E rows of 16 (f32) ----
__global__ void k_relmean(const float* __restrict__ rel, float* __restrict__ relmean, int E){
  __shared__ float red[256][16];
  float s[16];
#pragma unroll
  for(int j=0;j<16;j++) s[j]=0.f;
  for(int r = blockIdx.x*blockDim.x + threadIdx.x; r < E; r += gridDim.x*blockDim.x){
    const float4* p = (const float4*)(rel + (size_t)r*16);
    float4 a=p[0], b=p[1], c=p[2], d=p[3];
    s[0]+=a.x; s[1]+=a.y; s[2]+=a.z; s[3]+=a.w;
    s[4]+=b.x; s[5]+=b.y; s[6]+=b.z; s[7]+=b.w;
    s[8]+=c.x; s[9]+=c.y; s[10]+=c.z; s[11]+=c.w;
    s[12]+=d.x; s[13]+=d.y; s[14]+=d.z; s[15]+=d.w;
  }
  int tid = threadIdx.x;
#pragma unroll
  for(int j=0;j<16;j++) red[tid][j]=s[j];
  __syncthreads();
  for(int off=128; off>0; off>>=1){
    if(tid<off){
#pragma unroll
      for(int j=0;j<16;j++) red[tid][j]+=red[tid+off][j];
    }
    __syncthreads();
  }
  if(tid<16) atomicAdd(relmean+tid, red[0][tid]*(1.0f/(float)E));
}

// ---- CSR build ----
__global__ void k_count(const int* __restrict__ edges, int* __restrict__ counts, int E, int N){
  int Et = E + N;
  int e = blockIdx.x*blockDim.x + threadIdx.x;
  if(e>=Et) return;
  int d = (e<E) ? edges[E+e] : (e-E);
  if(d<0) d=0; if(d>=N) d=N-1;
  atomicAdd(counts+d, 1);
}

__global__ void k_scan(const int* __restrict__ counts, int* __restrict__ rowstart,
                       int* __restrict__ cursor, int N){
  __shared__ int part[1024];
  int tid = threadIdx.x;
  int chunk = (N + 1023) >> 10;
  int lo = tid*chunk, hi = lo+chunk; if(hi>N) hi=N; if(lo>N) lo=N;
  int s=0;
  for(int i=lo;i<hi;i++) s += counts[i];
  part[tid]=s;
  __syncthreads();
  for(int off=1; off<1024; off<<=1){
    int v = (tid>=off) ? part[tid-off] : 0;
    __syncthreads();
    part[tid] += v;
    __syncthreads();
  }
  int run = (tid==0) ? 0 : part[tid-1];
  for(int i=lo;i<hi;i++){ rowstart[i]=run; cursor[i]=run; run += counts[i]; }
  if(tid==1023) rowstart[N] = part[1023];
}

__global__ void k_scatter(const int* __restrict__ edges, int* __restrict__ cursor,
                          int* __restrict__ adj_src, int* __restrict__ adj_eid, int E, int N){
  int Et = E + N;
  int e = blockIdx.x*blockDim.x + threadIdx.x;
  if(e>=Et) return;
  int s, d;
  if(e<E){ s=edges[e]; d=edges[E+e]; } else { s=e-E; d=s; }
  if(d<0) d=0; if(d>=N) d=N-1;
  int pos = atomicAdd(cursor+d, 1);
  adj_src[pos]=s; adj_eid[pos]=e;
}

// ---- embedding + input projection: h[N][64] (f32) ----
__global__ void k_embed(const float* __restrict__ nodes,
                        const float* __restrict__ time_emb, const float* __restrict__ type_emb,
                        const float* __restrict__ biway_emb, const float* __restrict__ islink_emb,
                        const float* __restrict__ projw, const float* __restrict__ projb,
                        float* __restrict__ h, int N){
  __shared__ float W[64][65];
  __shared__ float h0[4][64];
  int tid = threadIdx.x;
  for(int i=tid; i<64*64; i+=256) W[i>>6][i&63] = projw[i];
  __syncthreads();
  int wave = tid>>6, lane = tid&63;
  int node = blockIdx.x*4 + wave;
  if(node<N){
    const float* nr = nodes + (size_t)node*20;
    float v; int c = lane;
    if(c<16){
      int t=(int)nr[0]; t = t<0?0:(t>287?287:t);
      v = time_emb[t*16+c];
    } else if(c<32){
      int ty=(int)nr[1]; ty = ty<0?0:(ty>15?15:ty);
      v = type_emb[ty*16+(c-16)];
    } else if(c<40){
      int bw=(int)nr[2]; bw = bw<0?0:(bw>1?1:bw);
      v = biway_emb[bw*8+(c-32)];
    } else if(c<48){
      int il=(int)nr[3]; il = il<0?0:(il>1?1:il);
      v = islink_emb[il*8+(c-40)];
    } else {
      v = nr[4 + (c-48)];
    }
    h0[wave][lane]=v;
  }
  __syncthreads();
  if(node<N){
    float acc = projb[lane];
#pragma unroll
    for(int k=0;k<64;k++) acc += W[lane][k]*h0[wave][k];
    h[(size_t)node*64+lane]=acc;
  }
}

// ---- xl/xr = h @ {wl,wr}.T + {bl,br}, stored bf16. 16 nodes/block ----
__global__ void k_xlr(const float* __restrict__ h,
                      const float* __restrict__ wl, const float* __restrict__ bl,
                      const float* __restrict__ wr, const float* __restrict__ br,
                      u16* __restrict__ xl, u16* __restrict__ xr, int N){
  __shared__ float hs[NT*64];
  int tid = threadIdx.x;
  int base = blockIdx.x*NT;
  int nvalid = N - base; if(nvalid > NT) nvalid = NT;
  if(nvalid == NT){
    *(float4*)(hs + tid*4) = *(const float4*)(h + (size_t)base*64 + tid*4);
  } else {
    for(int i=tid; i<NT*64; i+=256) hs[i] = (i < nvalid*64) ? h[(size_t)base*64+i] : 0.f;
  }
  __syncthreads();
  int o = tid;   // output channel 0..255
  const float4* wl4 = (const float4*)(wl + (size_t)o*64);
  const float4* wr4 = (const float4*)(wr + (size_t)o*64);
  float blv = bl[o], brv = br[o];
  float accl[NT], accr[NT];
#pragma unroll
  for(int n=0;n<NT;n++){ accl[n]=blv; accr[n]=brv; }
  for(int kk=0; kk<16; kk++){
    float4 a = wl4[kk];
    float4 b = wr4[kk];
#pragma unroll
    for(int n=0;n<NT;n++){
      float4 hv = *(const float4*)(hs + n*64 + kk*4);
      accl[n] += a.x*hv.x + a.y*hv.y + a.z*hv.z + a.w*hv.w;
      accr[n] += b.x*hv.x + b.y*hv.y + b.z*hv.z + b.w*hv.w;
    }
  }
  for(int n=0;n<nvalid;n++){
    xl[(size_t)(base+n)*HHID + o] = f2bf(accl[n]);
    xr[(size_t)(base+n)*HHID + o] = f2bf(accr[n]);
  }
}

// ---- fused per-node: edge logits + online softmax + aggregation + residual ----
// 2-deep software pipeline: while computing edge p, data for p+1 and indices
// for p+2 are in flight. Branchless online-softmax update.
__global__ void k_fused(const int* __restrict__ rowstart, const int* __restrict__ adj_src,
                        const int* __restrict__ adj_eid,
                        const float* __restrict__ relation, const float* __restrict__ relmean,
                        const float* __restrict__ we, const float* __restrict__ att,
                        const u16* __restrict__ xl, const u16* __restrict__ xr,
                        const float* __restrict__ gat_b,
                        float* __restrict__ h, int N, int E, float* __restrict__ outp){
  const int lane = threadIdx.x & 63;
  const int sub = lane & 15;
  const int wid = (blockIdx.x*blockDim.x + threadIdx.x) >> 6;
  const int nw  = (gridDim.x*blockDim.x) >> 6;

  // per-wave constants: this lane's 4 we-rows (64 floats), att quad
  float wreg[64];
  {
    const float4* wp = (const float4*)(we + (size_t)lane*64);
#pragma unroll
    for(int i=0;i<16;i++){
      float4 t = wp[i];
      wreg[i*4+0]=t.x; wreg[i*4+1]=t.y; wreg[i*4+2]=t.z; wreg[i*4+3]=t.w;
    }
  }
  const float4 at4 = *(const float4*)(att + lane*4);

  for(int node = wid; node < N; node += nw){
    const int lo = rowstart[node], hi = rowstart[node+1];
    uint2 pb = *(const uint2*)(xr + (size_t)node*HHID + lane*4);
    float bv0=bflo(pb.x), bv1=bfhi(pb.x), bv2=bflo(pb.y), bv3=bfhi(pb.y);

    float m = -1e30f, den = 0.f;
    float a0=0.f, a1=0.f, a2=0.f, a3=0.f;

    // pipeline prologue: idx(lo), idx(lo+1), data(lo)
    int eidA=0, svA=0, eidB=0, svB=0;
    if(lo < hi){ eidA = adj_eid[lo]; svA = adj_src[lo]; }
    if(lo+1 < hi){ eidB = adj_eid[lo+1]; svB = adj_src[lo+1]; }
    float rcA[16]; uint2 paA = make_uint2(0u,0u);
    if(lo < hi){
      int sv = svA; if(sv<0) sv=0; if(sv>=N) sv=N-1;
      const float4* rp = (eidA < E) ? (const float4*)(relation + (size_t)eidA*16)
                                    : (const float4*)relmean;
      float4 q0=rp[0], q1=rp[1], q2=rp[2], q3=rp[3];
      rcA[0]=q0.x; rcA[1]=q0.y; rcA[2]=q0.z; rcA[3]=q0.w;
      rcA[4]=q1.x; rcA[5]=q1.y; rcA[6]=q1.z; rcA[7]=q1.w;
      rcA[8]=q2.x; rcA[9]=q2.y; rcA[10]=q2.z; rcA[11]=q2.w;
      rcA[12]=q3.x; rcA[13]=q3.y; rcA[14]=q3.z; rcA[15]=q3.w;
      paA = *(const uint2*)(xl + (size_t)sv*HHID + lane*4);
    }

    for(int p=lo; p<hi; p++){
      // stage 1: data loads for p+1 (indices resident in eidB/svB)
      float rcB[16]; uint2 paB = make_uint2(0u,0u);
      if(p+1 < hi){
        int sv = svB; if(sv<0) sv=0; if(sv>=N) sv=N-1;
        const float4* rp = (eidB < E) ? (const float4*)(relation + (size_t)eidB*16)
                                      : (const float4*)relmean;
        float4 q0=rp[0], q1=rp[1], q2=rp[2], q3=rp[3];
        rcB[0]=q0.x; rcB[1]=q0.y; rcB[2]=q0.z; rcB[3]=q0.w;
        rcB[4]=q1.x; rcB[5]=q1.y; rcB[6]=q1.z; rcB[7]=q1.w;
        rcB[8]=q2.x; rcB[9]=q2.y; rcB[10]=q2.z; rcB[11]=q2.w;
        rcB[12]=q3.x; rcB[13]=q3.y; rcB[14]=q3.z; rcB[15]=q3.w;
        paB = *(const uint2*)(xl + (size_t)sv*HHID + lane*4);
      }
      // stage 2: idx loads for p+2
      int eidC=0, svC=0;
      if(p+2 < hi){ eidC = adj_eid[p+2]; svC = adj_src[p+2]; }

      // stage 3: compute edge p on resident rcA/paA
      float av0=bflo(paA.x), av1=bfhi(paA.x), av2=bflo(paA.y), av3=bfhi(paA.y);
      float c = 0.f;
#pragma unroll
      for(int j=0;j<4;j++){
        float ep = 0.f;
#pragma unroll
        for(int k=0;k<16;k++) ep += rcA[k]*wreg[j*16+k];
        float avj = (j==0)?av0:(j==1)?av1:(j==2)?av2:av3;
        float bvj = (j==0)?bv0:(j==1)?bv1:(j==2)?bv2:bv3;
        float mm = avj + bvj + ep;
        mm = (mm>0.f) ? mm : 0.2f*mm;
        float atj = (j==0)?at4.x:(j==1)?at4.y:(j==2)?at4.z:at4.w;
        c += mm*atj;
      }
      c += __shfl_xor(c, 1);
      c += __shfl_xor(c, 2);
      c += __shfl_xor(c, 4);
      c += __shfl_xor(c, 8);

      // branchless online softmax update
      float newm = fmaxf(m, c);
      float scale = __expf(m - newm);   // 0 on first iteration
      float wgt   = __expf(c - newm);
      den = den*scale + wgt;
      a0 = a0*scale + wgt*av0;
      a1 = a1*scale + wgt*av1;
      a2 = a2*scale + wgt*av2;
      a3 = a3*scale + wgt*av3;
      m = newm;

      // rotate pipeline
#pragma unroll
      for(int k=0;k<16;k++) rcA[k]=rcB[k];
      paA = paB;
      eidB = eidC; svB = svC;
    }

    float inv = 1.0f/den;
    float v0=a0*inv, v1=a1*inv, v2=a2*inv, v3=a3*inv;
    v0 += __shfl_xor(v0,16); v0 += __shfl_xor(v0,32);
    v1 += __shfl_xor(v1,16); v1 += __shfl_xor(v1,32);
    v2 += __shfl_xor(v2,16); v2 += __shfl_xor(v2,32);
    v3 += __shfl_xor(v3,16); v3 += __shfl_xor(v3,32);
    if(lane < 16){
      int cb = sub*4;
      float4 hv = *(const float4*)(h + (size_t)node*64 + cb);
      const float4 gb = *(const float4*)(gat_b + cb);
      float o0 = fmaxf(0.25f*v0 + gb.x + hv.x, 0.f);
      float o1 = fmaxf(0.25f*v1 + gb.y + hv.y, 0.f);
      float o2 = fmaxf(0.25f*v2 + gb.z + hv.z, 0.f);
      float o3 = fmaxf(0.25f*v3 + gb.w + hv.w, 0.f);
      *(float4*)(h + (size_t)node*64 + cb) = make_float4(o0,o1,o2,o3);
      if(outp) *(float4*)(outp + (size_t)node*64 + cb) = make_float4(o0,o1,o2,o3);
    }
  }
}

extern "C" void kernel_launch(void* const* d_in, const int* in_sizes, int n_in,
                              void* d_out, int out_size, void* d_ws, size_t ws_size,
                              hipStream_t stream) {
  const float* nodes     = (const float*)d_in[0];
  const int*   edges     = (const int*)d_in[1];
  const float* relation  = (const float*)d_in[2];
  const float* time_emb  = (const float*)d_in[3];
  const float* type_emb  = (const float*)d_in[4];
  const float* biway_emb = (const float*)d_in[5];
  const float* islink_emb= (const float*)d_in[6];
  const float* proj_w    = (const float*)d_in[7];
  const float* proj_b    = (const float*)d_in[8];
  const float* lin_l_w   = (const float*)d_in[9];
  const float* lin_l_b   = (const float*)d_in[10];
  const float* lin_r_w   = (const float*)d_in[11];
  const float* lin_r_b   = (const float*)d_in[12];
  const float* lin_e_w   = (const float*)d_in[13];
  const float* att       = (const float*)d_in[14];
  const float* gat_b     = (const float*)d_in[15];

  const int N  = in_sizes[0] / 20;
  const int E  = in_sizes[1] / 2;
  const int Et = E + N;

  size_t off = 0;
  auto alloc = [&](size_t bytes)->size_t {
    size_t p = off;
    off += ((bytes + 255) / 256) * 256;
    return p;
  };
  size_t o_h        = alloc((size_t)N*64*4);        // f32
  size_t o_xl       = alloc((size_t)N*HHID*2);      // bf16
  size_t o_xr       = alloc((size_t)N*HHID*2);      // bf16
  size_t o_relmean  = alloc(64*4);
  size_t o_counts   = alloc((size_t)N*4);
  size_t o_rowstart = alloc((size_t)(N+1)*4);
  size_t o_cursor   = alloc((size_t)(N+1)*4);
  size_t o_adjsrc   = alloc((size_t)Et*4);
  size_t o_adjeid   = alloc((size_t)Et*4);

  if (off > ws_size) {
    TopoAggregator_33217277067466_kernel<<<2048, 256, 0, stream>>>(
        (float*)d_out, out_size, 100.0f);   // marker ~100: ws too small
    return;
  }

  char* w = (char*)d_ws;
  float* h        = (float*)(w + o_h);
  u16*   xl       = (u16*)(w + o_xl);
  u16*   xr       = (u16*)(w + o_xr);
  float* relmean  = (float*)(w + o_relmean);
  int*   counts   = (int*)(w + o_counts);
  int*   rowstart = (int*)(w + o_rowstart);
  int*   cursor   = (int*)(w + o_cursor);
  int*   adj_src  = (int*)(w + o_adjsrc);
  int*   adj_eid  = (int*)(w + o_adjeid);

  k_zero<<<(N+255)/256, 256, 0, stream>>>(counts, relmean, N);
  k_relmean<<<64, 256, 0, stream>>>(relation, relmean, E);
  k_count<<<(Et+255)/256, 256, 0, stream>>>(edges, counts, E, N);
  k_scan<<<1, 1024, 0, stream>>>(counts, rowstart, cursor, N);
  k_scatter<<<(Et+255)/256, 256, 0, stream>>>(edges, cursor, adj_src, adj_eid, E, N);

  k_embed<<<(N+3)/4, 256, 0, stream>>>(nodes, time_emb, type_emb, biway_emb, islink_emb,
                                       proj_w, proj_b, h, N);

  for(int l=0; l<2; l++){
    k_xlr<<<(N+NT-1)/NT, 256, 0, stream>>>(h,
        lin_l_w + (size_t)l*HHID*64, lin_l_b + (size_t)l*HHID,
        lin_r_w + (size_t)l*HHID*64, lin_r_b + (size_t)l*HHID,
        xl, xr, N);
    k_fused<<<4096, 256, 0, stream>>>(rowstart, adj_src, adj_eid,
        relation, relmean,
        lin_e_w + (size_t)l*HHID*16, att + (size_t)l*HEADS*64,
        xl, xr, gat_b + (size_t)l*64,
        h, N, E,
        (l==1) ? (float*)d_out : (float*)nullptr);
  }
  k_marker<<<1, 64, 0, stream>>>(rowstart, h, (float*)d_out, N, Et);
}